// Round 4
// baseline (106226.831 us; speedup 1.0000x reference)
//
#include <hip/hip_runtime.h>
#include <math.h>

// Problem constants
#define BB   32
#define SS   2048
#define DD   1024
#define DCC  512
#define VV   256

// ---------------------------------------------------------------------------
// helpers
// ---------------------------------------------------------------------------
__device__ __forceinline__ float sigmoid_f(float x) {
  return 1.0f / (1.0f + __expf(-x));
}
__device__ __forceinline__ float tanh_f(float x) {
  return 1.0f - 2.0f / (__expf(2.0f * x) + 1.0f);
}

// Multi-value wave reduction, sequential halving. Start: each of 64 lanes
// holds N partial values (lane = k-slice). After calls with o = 1,2,4,...:
// value idx migrates to lane idx (idx bits = lane bits, LSB first).
template <int N>
__device__ __forceinline__ void pair_reduce(float* v, int lane, int o) {
#pragma unroll
  for (int k = 0; k < (N >> 1); ++k) {
    float a = v[2 * k], b = v[2 * k + 1];
    float sent = (lane & o) ? a : b;
    float recv = __shfl_xor(sent, o);
    v[k] = ((lane & o) ? b : a) + recv;
  }
}

// Two-level 256-block sense barrier (per-machine, device scope).
// bar layout (uints): [0]=generation, [32]=root counter, [64+g*32]=group-g
// counter (16 groups of 16 blocks), distinct 128B lines each.
__device__ __forceinline__ void grid_barrier(unsigned* bar, int grp) {
  __syncthreads();
  if (threadIdx.x == 0) {
    __threadfence();  // release: make our h/rh writes visible device-wide
    unsigned gen = __hip_atomic_load(&bar[0], __ATOMIC_RELAXED, __HIP_MEMORY_SCOPE_AGENT);
    unsigned p = __hip_atomic_fetch_add(&bar[64 + (grp << 5)], 1u,
                                        __ATOMIC_RELAXED, __HIP_MEMORY_SCOPE_AGENT);
    if (p == 15u) {
      unsigned q = __hip_atomic_fetch_add(&bar[32], 1u,
                                          __ATOMIC_RELAXED, __HIP_MEMORY_SCOPE_AGENT);
      if (q == 15u) {
        __hip_atomic_store(&bar[32], 0u, __ATOMIC_RELAXED, __HIP_MEMORY_SCOPE_AGENT);
#pragma unroll
        for (int i = 0; i < 16; ++i)
          __hip_atomic_store(&bar[64 + (i << 5)], 0u, __ATOMIC_RELAXED,
                             __HIP_MEMORY_SCOPE_AGENT);
        __hip_atomic_store(&bar[0], gen + 1u, __ATOMIC_RELEASE,
                           __HIP_MEMORY_SCOPE_AGENT);
      }
    }
    while (__hip_atomic_load(&bar[0], __ATOMIC_RELAXED, __HIP_MEMORY_SCOPE_AGENT) == gen) {
      __builtin_amdgcn_s_sleep(2);
    }
    __threadfence();  // acquire: drop stale cached h/rh before reading
  }
  __syncthreads();
}

// ---------------------------------------------------------------------------
// 1) Transpose recurrent weight halves: whT[g][j][k] = W_g[1024+k][j]
// ---------------------------------------------------------------------------
__global__ __launch_bounds__(256) void k_transpose(
    const float* __restrict__ Wr, const float* __restrict__ Wu,
    const float* __restrict__ Wc, float* __restrict__ whT) {
  __shared__ float t[32][33];
  int bid = blockIdx.x;
  int g = bid >> 10;
  int rr = bid & 1023;
  int kt = rr >> 5, jt = rr & 31;
  const float* W = (g == 0) ? Wr : (g == 1) ? Wu : Wc;
  int x = threadIdx.x & 31, y = threadIdx.x >> 5;  // 32 x 8
#pragma unroll
  for (int i = 0; i < 4; ++i)
    t[y + 8 * i][x] = W[(size_t)(1024 + kt * 32 + y + 8 * i) * 1024 + jt * 32 + x];
  __syncthreads();
#pragma unroll
  for (int i = 0; i < 4; ++i)
    whT[(size_t)g * 1048576 + (size_t)(jt * 32 + y + 8 * i) * 1024 + kt * 32 + x] =
        t[x][y + 8 * i];
}

// ---------------------------------------------------------------------------
// 2) Per-vocab input projections (+bias): xpre[g][v][j] = emb(v).W_g[:1024,j]+b_g[j]
// ---------------------------------------------------------------------------
__global__ __launch_bounds__(256) void k_xpre(
    const float* __restrict__ Er, const float* __restrict__ Ei,
    const float* __restrict__ Wr, const float* __restrict__ Wu, const float* __restrict__ Wc,
    const float* __restrict__ br, const float* __restrict__ bu, const float* __restrict__ bc,
    float* __restrict__ xpre) {
  __shared__ float emb[4][1024];
  int bid = blockIdx.x;          // 0..191
  int g = bid / 64, vg = bid % 64;
  int v0 = vg * 4;
  int tid = threadIdx.x;
  for (int idx = tid; idx < 4096; idx += 256) {
    int v = idx >> 10, k = idx & 1023;
    emb[v][k] = (k < 512) ? Er[(size_t)(v0 + v) * 512 + k]
                          : Ei[(size_t)(v0 + v) * 512 + k - 512];
  }
  __syncthreads();
  const float* W = (g == 0) ? Wr : (g == 1) ? Wu : Wc;
  const float* bias = (g == 0) ? br : (g == 1) ? bu : bc;
  float acc[4][4];
#pragma unroll
  for (int v = 0; v < 4; ++v)
#pragma unroll
    for (int jj = 0; jj < 4; ++jj) acc[v][jj] = bias[tid + jj * 256];
  for (int k = 0; k < 1024; ++k) {
    float w0 = W[(size_t)k * 1024 + tid];
    float w1 = W[(size_t)k * 1024 + tid + 256];
    float w2 = W[(size_t)k * 1024 + tid + 512];
    float w3 = W[(size_t)k * 1024 + tid + 768];
#pragma unroll
    for (int v = 0; v < 4; ++v) {
      float e = emb[v][k];
      acc[v][0] = fmaf(e, w0, acc[v][0]);
      acc[v][1] = fmaf(e, w1, acc[v][1]);
      acc[v][2] = fmaf(e, w2, acc[v][2]);
      acc[v][3] = fmaf(e, w3, acc[v][3]);
    }
  }
#pragma unroll
  for (int v = 0; v < 4; ++v)
#pragma unroll
    for (int jj = 0; jj < 4; ++jj)
      xpre[(size_t)(g * 256 + v0 + v) * 1024 + tid + jj * 256] = acc[v][jj];
}

// ---------------------------------------------------------------------------
// 3) Persistent GRU scan, TWO independent 16-row machines.
//    512 blocks x 256 threads, 2 blocks/CU (48KB LDS each).
//    machine = blockIdx>>8 (rows m*16..m*16+15), cb = blockIdx&255 owns
//    cols cb*4..cb*4+3 of r,u,c,h; weights LDS-resident for all 2048 steps.
//    Per machine: private 2-level barrier over its 256 blocks; h / r*h
//    exchanged via global. Machines are independent -> no cross-machine
//    deadlock possible; co-resident machine waves hide each other's
//    barrier latency on the shared SIMDs.
//    Wave tiling: 4 waves x 4 rows; lane = k-slice (4 floats).
// ---------------------------------------------------------------------------
__global__ __launch_bounds__(256, 2) void k_scan(
    const int* __restrict__ tok, const float* __restrict__ xpre,
    const float* __restrict__ whT, float* h, float* rh,
    float* __restrict__ out_nr, float* __restrict__ out_ni,
    float* __restrict__ out_fcr, float* __restrict__ out_fci, unsigned* bar) {
  __shared__ float wa[8][1024];   // cols 0..3 = Whr[j0..], 4..7 = Whu[j0..]
  __shared__ float wcl[4][1024];  // Whc[j0..]

  const int tid = threadIdx.x;
  const int machine = blockIdx.x >> 8;   // 0/1; blocks c and c+256 share a CU
  const int cb = blockIdx.x & 255;       // column block
  const int j0 = cb * 4;
  const int grp = cb >> 4;
  unsigned* mybar = bar + (machine << 10);

  for (int idx = tid; idx < 8192; idx += 256) {
    int c = idx >> 10, k = idx & 1023;
    size_t gofs = (c < 4) ? 0u : 1048576u;
    wa[c][k] = whT[gofs + (size_t)(j0 + (c & 3)) * 1024 + k];
  }
  for (int idx = tid; idx < 4096; idx += 256) {
    int c = idx >> 10, k = idx & 1023;
    wcl[c][k] = whT[2097152u + (size_t)(j0 + c) * 1024 + k];
  }
  __syncthreads();

  // seed anti-phase: machine 1 lags ~2k cycles so its compute overlaps
  // machine 0's barrier waits (and vice versa thereafter).
  if (machine == 1) {
    __builtin_amdgcn_s_sleep(16);
    __builtin_amdgcn_s_sleep(16);
  }

  const int wv = tid >> 6;
  const int lane = tid & 63;
  const int r0 = machine * 16 + wv * 4;  // wave's 4 global batch rows
  const int kl = lane << 2;              // lane k-slice base (floats)
  // phase-A result mapping: idx = lane&31 -> (row idx>>3, gate-col idx&7)
  const int ia = (lane & 31) >> 3;
  const int arow = r0 + ia;
  const int ac = lane & 7;               // 0..3 = r cols, 4..7 = u cols
  const int acol = j0 + (ac & 3);
  // phase-B result mapping: idx = lane&15 -> (row idx>>2, c-col idx&3)
  const int ib = (lane & 15) >> 2;
  const int brow = r0 + ib;
  const int bcol = j0 + (lane & 3);
  const int usrc = (ib << 3) + 4 + (lane & 3);  // lane holding u for (ib, col)

  float u_s = 0.f;

  for (int t = 0; t < SS; ++t) {
    // per-lane scalar prefetch (latency hides under phase-A GEMM)
    const int tva = tok[(size_t)arow * SS + t];
    const float xru_s = (ac < 4)
        ? xpre[(size_t)tva * 1024 + acol]
        : xpre[262144u + (size_t)tva * 1024 + acol];
    const float ho_s = h[(size_t)arow * 1024 + acol];   // for r*h
    const int tvb = tok[(size_t)brow * SS + t];
    const float xc_s = xpre[524288u + (size_t)tvb * 1024 + bcol];
    const float hob_s = h[(size_t)brow * 1024 + bcol];  // for state update

    // ---------------- Phase A: vals[i*8+c] = sum_k h[r0+i][k]*wa[c][k]
    float vals[32];
#pragma unroll
    for (int q = 0; q < 32; ++q) vals[q] = 0.f;

    {
      float4 hva[4], hvb[4];
#pragma unroll
      for (int i = 0; i < 4; ++i)
        hva[i] = *(const float4*)(h + (size_t)(r0 + i) * 1024 + kl);

      auto stepA = [&](float4(&cur)[4], float4(&nxt)[4], int g) {
        if (g < 3) {
          const int kn = ((g + 1) << 8) + kl;
#pragma unroll
          for (int i = 0; i < 4; ++i)
            nxt[i] = *(const float4*)(h + (size_t)(r0 + i) * 1024 + kn);
        }
        const int k0 = (g << 8) + kl;
#pragma unroll
        for (int c = 0; c < 8; ++c) {
          const float4 wv4 = *(const float4*)(&wa[c][k0]);
#pragma unroll
          for (int i = 0; i < 4; ++i) {
            vals[i * 8 + c] = fmaf(cur[i].x, wv4.x, vals[i * 8 + c]);
            vals[i * 8 + c] = fmaf(cur[i].y, wv4.y, vals[i * 8 + c]);
            vals[i * 8 + c] = fmaf(cur[i].z, wv4.z, vals[i * 8 + c]);
            vals[i * 8 + c] = fmaf(cur[i].w, wv4.w, vals[i * 8 + c]);
          }
        }
      };
      stepA(hva, hvb, 0);
      stepA(hvb, hva, 1);
      stepA(hva, hvb, 2);
      stepA(hvb, hva, 3);
    }

    pair_reduce<32>(vals, lane, 1);
    pair_reduce<16>(vals, lane, 2);
    pair_reduce<8>(vals, lane, 4);
    pair_reduce<4>(vals, lane, 8);
    pair_reduce<2>(vals, lane, 16);
    // vals[0]: preact for idx=lane&31 summed over this 32-lane half's k
    const float pre_a = vals[0] + __shfl_xor(vals[0], 32);

    const float gate = sigmoid_f(pre_a + xru_s);
    if (ac < 4) {
      if (lane < 32) rh[(size_t)arow * 1024 + acol] = gate * ho_s;  // r*h
    } else {
      u_s = gate;                                                   // u
    }
    grid_barrier(mybar, grp);

    // ---------------- Phase B: v2[i*4+c] = sum_k rh[r0+i][k]*wcl[c][k]
    float v2[16];
#pragma unroll
    for (int q = 0; q < 16; ++q) v2[q] = 0.f;

    {
      float4 rva[4], rvb[4];
#pragma unroll
      for (int i = 0; i < 4; ++i)
        rva[i] = *(const float4*)(rh + (size_t)(r0 + i) * 1024 + kl);

      auto stepB = [&](float4(&cur)[4], float4(&nxt)[4], int g) {
        if (g < 3) {
          const int kn = ((g + 1) << 8) + kl;
#pragma unroll
          for (int i = 0; i < 4; ++i)
            nxt[i] = *(const float4*)(rh + (size_t)(r0 + i) * 1024 + kn);
        }
        const int k0 = (g << 8) + kl;
#pragma unroll
        for (int c = 0; c < 4; ++c) {
          const float4 wv4 = *(const float4*)(&wcl[c][k0]);
#pragma unroll
          for (int i = 0; i < 4; ++i) {
            v2[i * 4 + c] = fmaf(cur[i].x, wv4.x, v2[i * 4 + c]);
            v2[i * 4 + c] = fmaf(cur[i].y, wv4.y, v2[i * 4 + c]);
            v2[i * 4 + c] = fmaf(cur[i].z, wv4.z, v2[i * 4 + c]);
            v2[i * 4 + c] = fmaf(cur[i].w, wv4.w, v2[i * 4 + c]);
          }
        }
      };
      stepB(rva, rvb, 0);
      stepB(rvb, rva, 1);
      stepB(rva, rvb, 2);
      stepB(rvb, rva, 3);
    }

    pair_reduce<16>(v2, lane, 1);
    pair_reduce<8>(v2, lane, 2);
    pair_reduce<4>(v2, lane, 4);
    pair_reduce<2>(v2, lane, 8);
    // v2[0]: idx=lane&15 over this 16-lane group's k; fold groups:
    float cpre = v2[0] + __shfl_xor(v2[0], 16);
    cpre += __shfl_xor(cpre, 32);

    const float cc = tanh_f(cpre + xc_s);
    const float uu = __shfl(u_s, usrc);
    const float hn = (1.f - uu) * hob_s + uu * cc;
    if (lane < 16) {
      h[(size_t)brow * 1024 + bcol] = hn;
      float* dst = (j0 < 512)
                       ? (out_nr + ((size_t)brow * SS + t) * 512 + bcol)
                       : (out_ni + ((size_t)brow * SS + t) * 512 + bcol - 512);
      *dst = hn;
      if (t == SS - 1) {
        float* f = (j0 < 512) ? (out_fcr + (size_t)brow * 512 + bcol)
                              : (out_fci + (size_t)brow * 512 + bcol - 512);
        *f = hn;
      }
    }
    grid_barrier(mybar, grp);
  }
}

// ---------------------------------------------------------------------------
// 4) Fused tail: LayerNorm (in LDS, writes normalized n_r/n_i back) + logits.
// ---------------------------------------------------------------------------
__global__ __launch_bounds__(256) void k_tail(
    float* __restrict__ nr, float* __restrict__ ni,  // raw in, normalized out
    const float* __restrict__ sr, const float* __restrict__ br_,
    const float* __restrict__ si, const float* __restrict__ bi_,
    const float* __restrict__ Wrc, const float* __restrict__ Wic,
    const float* __restrict__ brc, const float* __restrict__ bic,
    float* __restrict__ out) {
  __shared__ float tr[16][512];
  __shared__ float ti[16][512];
  const long long r0 = (long long)blockIdx.x * 16;
  const int tid = threadIdx.x;
  for (int idx = tid; idx < 16 * 512; idx += 256) {
    int rr = idx >> 9, k = idx & 511;
    tr[rr][k] = nr[(r0 + rr) * 512 + k];
    ti[rr][k] = ni[(r0 + rr) * 512 + k];
  }
  __syncthreads();

  // LayerNorm: 32 (array,row) pairs over 4 waves
  {
    const int wv = tid >> 6, ln = tid & 63;
#pragma unroll
    for (int pp = 0; pp < 8; ++pp) {
      const int p = wv * 8 + pp;
      const int arr = p >> 4;   // 0 = real, 1 = imag
      const int row = p & 15;
      float* t = arr ? &ti[row][0] : &tr[row][0];
      float v[8];
      float s = 0.f, q = 0.f;
#pragma unroll
      for (int j = 0; j < 8; ++j) {
        v[j] = t[ln + j * 64];
        s += v[j];
        q += v[j] * v[j];
      }
#pragma unroll
      for (int o = 32; o >= 1; o >>= 1) {
        s += __shfl_xor(s, o);
        q += __shfl_xor(q, o);
      }
      const float mean = s * (1.f / 512.f);
      const float rstd = rsqrtf(q * (1.f / 512.f) - mean * mean + 1e-6f);
      const float* sc = arr ? si : sr;
      const float* bs = arr ? bi_ : br_;
      float* gout = (arr ? ni : nr) + (r0 + row) * 512;
#pragma unroll
      for (int j = 0; j < 8; ++j) {
        const int k = ln + j * 64;
        float n = (v[j] - mean) * rstd * sc[k] + bs[k];
        t[k] = n;
        gout[k] = n;
      }
    }
  }
  __syncthreads();

  // logits GEMM: thread = one vocab column, 16 rows each.
  const int c = tid;
  float aR[16], aI[16];
#pragma unroll
  for (int i = 0; i < 16; ++i) { aR[i] = 0.f; aI[i] = 0.f; }
  for (int k0 = 0; k0 < 512; k0 += 4) {
    float wr[4], wi[4];
#pragma unroll
    for (int i = 0; i < 4; ++i) {
      wr[i] = Wrc[(size_t)(k0 + i) * 256 + c];
      wi[i] = Wic[(size_t)(k0 + i) * 256 + c];
    }
#pragma unroll
    for (int rrr = 0; rrr < 16; ++rrr) {
      const float4 vr = *(const float4*)(&tr[rrr][k0]);
      const float4 vi = *(const float4*)(&ti[rrr][k0]);
      aR[rrr] = fmaf(vr.x, wr[0], aR[rrr]);
      aR[rrr] = fmaf(vr.y, wr[1], aR[rrr]);
      aR[rrr] = fmaf(vr.z, wr[2], aR[rrr]);
      aR[rrr] = fmaf(vr.w, wr[3], aR[rrr]);
      aI[rrr] = fmaf(vi.x, wi[0], aI[rrr]);
      aI[rrr] = fmaf(vi.y, wi[1], aI[rrr]);
      aI[rrr] = fmaf(vi.z, wi[2], aI[rrr]);
      aI[rrr] = fmaf(vi.w, wi[3], aI[rrr]);
    }
  }
  const float bR = brc[c], bI = bic[c];
#pragma unroll
  for (int rrr = 0; rrr < 16; ++rrr) {
    float x = aR[rrr] + bR, y = aI[rrr] + bI;
    out[(r0 + rrr) * 256 + c] = x * x + y * y;
  }
}

// ---------------------------------------------------------------------------
// launch
// ---------------------------------------------------------------------------
extern "C" void kernel_launch(void* const* d_in, const int* in_sizes, int n_in,
                              void* d_out, int out_size, void* d_ws, size_t ws_size,
                              hipStream_t stream) {
  const int* tok = (const int*)d_in[0];
  const float* Er = (const float*)d_in[1];
  const float* Ei = (const float*)d_in[2];
  const float* Wr = (const float*)d_in[3];
  const float* br = (const float*)d_in[4];
  const float* Wu = (const float*)d_in[5];
  const float* bu = (const float*)d_in[6];
  const float* Wc = (const float*)d_in[7];
  const float* bc = (const float*)d_in[8];
  const float* lrs = (const float*)d_in[9];
  const float* lrb = (const float*)d_in[10];
  const float* lis = (const float*)d_in[11];
  const float* lib = (const float*)d_in[12];
  const float* Wrc = (const float*)d_in[13];
  const float* brc = (const float*)d_in[14];
  const float* Wic = (const float*)d_in[15];
  const float* bic = (const float*)d_in[16];

  float* out = (float*)d_out;
  float* fcr = out;                       // [32][512]
  float* fci = out + 16384;               // [32][512]
  float* nr = out + 32768;                // [32][2048][512]
  float* ni = nr + 33554432;              // [32][2048][512]
  float* lg = ni + 33554432;              // [32][2048][256]

  float* ws = (float*)d_ws;
  unsigned* bar = (unsigned*)ws;          // 2 machines x 4KB barrier state
  float* h = ws + 2048;                   // [32][1024]
  float* rh = ws + 34816;                 // [32][1024]
  float* xpre = ws + 67584;               // [3][256][1024]
  float* whT = ws + 854016;               // [3][1024][1024]

  hipMemsetAsync(bar, 0, 8192, stream);
  hipMemsetAsync(h, 0, 32 * 1024 * sizeof(float), stream);

  k_transpose<<<3072, 256, 0, stream>>>(Wr, Wu, Wc, whT);
  k_xpre<<<192, 256, 0, stream>>>(Er, Ei, Wr, Wu, Wc, br, bu, bc, xpre);
  k_scan<<<512, 256, 0, stream>>>(tok, xpre, whT, h, rh, nr, ni, fcr, fci, bar);
  k_tail<<<4096, 256, 0, stream>>>(nr, ni, lrs, lrb, lis, lib, Wrc, Wic, brc, bic, lg);
}

// Round 5
// 25877.847 us; speedup vs baseline: 4.1049x; 4.1049x over previous
//
#include <hip/hip_runtime.h>
#include <math.h>

// Problem constants
#define BB   32
#define SS   2048
#define DD   1024
#define DCC  512
#define VV   256

#define SCOPE_AGT __HIP_MEMORY_SCOPE_AGENT

// ---------------------------------------------------------------------------
// helpers
// ---------------------------------------------------------------------------
__device__ __forceinline__ float sigmoid_f(float x) {
  return 1.0f / (1.0f + __expf(-x));
}
__device__ __forceinline__ float tanh_f(float x) {
  return 1.0f - 2.0f / (__expf(2.0f * x) + 1.0f);
}

// Coherent (LLC-direct, sc0 sc1) accesses for cross-XCD h/rh exchange.
// Relaxed atomics: no cache flush, no forced waitcnt -> compiler pipelines.
__device__ __forceinline__ float2 ld_c2(const float* p) {
  unsigned long long u = __hip_atomic_load((const unsigned long long*)p,
                                           __ATOMIC_RELAXED, SCOPE_AGT);
  float2 r;
  r.x = __uint_as_float((unsigned)u);
  r.y = __uint_as_float((unsigned)(u >> 32));
  return r;
}
__device__ __forceinline__ float ld_c1(const float* p) {
  return __uint_as_float(
      __hip_atomic_load((const unsigned*)p, __ATOMIC_RELAXED, SCOPE_AGT));
}
__device__ __forceinline__ void st_c1(float* p, float v) {
  __hip_atomic_store((unsigned*)p, __float_as_uint(v), __ATOMIC_RELAXED,
                     SCOPE_AGT);
}

// Two-level 256-block barrier, monotone counters (never reset -> no reset
// race), round-numbered release. NO agent fences: data ordering comes from
// (a) producers' __syncthreads() draining vmcnt before arrival (stores are
// sc0sc1 write-through, complete at LLC), (b) consumers re-reading via
// sc0sc1 loads after release. bar layout (uints): [0]=release round,
// [32]=root counter, [64+g*32]=group-g counter; distinct 128B lines.
__device__ __forceinline__ void grid_barrier(unsigned* bar, int grp,
                                             unsigned round) {
  __syncthreads();
  if (threadIdx.x == 0) {
    unsigned p = __hip_atomic_fetch_add(&bar[64 + (grp << 5)], 1u,
                                        __ATOMIC_RELAXED, SCOPE_AGT);
    if ((p & 15u) == 15u) {
      unsigned q = __hip_atomic_fetch_add(&bar[32], 1u, __ATOMIC_RELAXED,
                                          SCOPE_AGT);
      if ((q & 15u) == 15u)
        __hip_atomic_store(&bar[0], round, __ATOMIC_RELAXED, SCOPE_AGT);
    }
    while (__hip_atomic_load(&bar[0], __ATOMIC_RELAXED, SCOPE_AGT) < round)
      __builtin_amdgcn_s_sleep(1);
  }
  __syncthreads();
}

// ---------------------------------------------------------------------------
// 1) Transpose recurrent weight halves: whT[g][j][k] = W_g[1024+k][j]
// ---------------------------------------------------------------------------
__global__ __launch_bounds__(256) void k_transpose(
    const float* __restrict__ Wr, const float* __restrict__ Wu,
    const float* __restrict__ Wc, float* __restrict__ whT) {
  __shared__ float t[32][33];
  int bid = blockIdx.x;
  int g = bid >> 10;
  int rr = bid & 1023;
  int kt = rr >> 5, jt = rr & 31;
  const float* W = (g == 0) ? Wr : (g == 1) ? Wu : Wc;
  int x = threadIdx.x & 31, y = threadIdx.x >> 5;  // 32 x 8
#pragma unroll
  for (int i = 0; i < 4; ++i)
    t[y + 8 * i][x] = W[(size_t)(1024 + kt * 32 + y + 8 * i) * 1024 + jt * 32 + x];
  __syncthreads();
#pragma unroll
  for (int i = 0; i < 4; ++i)
    whT[(size_t)g * 1048576 + (size_t)(jt * 32 + y + 8 * i) * 1024 + kt * 32 + x] =
        t[x][y + 8 * i];
}

// ---------------------------------------------------------------------------
// 2) Per-vocab input projections (+bias): xpre[g][v][j] = emb(v).W_g[:1024,j]+b_g[j]
// ---------------------------------------------------------------------------
__global__ __launch_bounds__(256) void k_xpre(
    const float* __restrict__ Er, const float* __restrict__ Ei,
    const float* __restrict__ Wr, const float* __restrict__ Wu, const float* __restrict__ Wc,
    const float* __restrict__ br, const float* __restrict__ bu, const float* __restrict__ bc,
    float* __restrict__ xpre) {
  __shared__ float emb[4][1024];
  int bid = blockIdx.x;          // 0..191
  int g = bid / 64, vg = bid % 64;
  int v0 = vg * 4;
  int tid = threadIdx.x;
  for (int idx = tid; idx < 4096; idx += 256) {
    int v = idx >> 10, k = idx & 1023;
    emb[v][k] = (k < 512) ? Er[(size_t)(v0 + v) * 512 + k]
                          : Ei[(size_t)(v0 + v) * 512 + k - 512];
  }
  __syncthreads();
  const float* W = (g == 0) ? Wr : (g == 1) ? Wu : Wc;
  const float* bias = (g == 0) ? br : (g == 1) ? bu : bc;
  float acc[4][4];
#pragma unroll
  for (int v = 0; v < 4; ++v)
#pragma unroll
    for (int jj = 0; jj < 4; ++jj) acc[v][jj] = bias[tid + jj * 256];
  for (int k = 0; k < 1024; ++k) {
    float w0 = W[(size_t)k * 1024 + tid];
    float w1 = W[(size_t)k * 1024 + tid + 256];
    float w2 = W[(size_t)k * 1024 + tid + 512];
    float w3 = W[(size_t)k * 1024 + tid + 768];
#pragma unroll
    for (int v = 0; v < 4; ++v) {
      float e = emb[v][k];
      acc[v][0] = fmaf(e, w0, acc[v][0]);
      acc[v][1] = fmaf(e, w1, acc[v][1]);
      acc[v][2] = fmaf(e, w2, acc[v][2]);
      acc[v][3] = fmaf(e, w3, acc[v][3]);
    }
  }
#pragma unroll
  for (int v = 0; v < 4; ++v)
#pragma unroll
    for (int jj = 0; jj < 4; ++jj)
      xpre[(size_t)(g * 256 + v0 + v) * 1024 + tid + jj * 256] = acc[v][jj];
}

// ---------------------------------------------------------------------------
// 3) Persistent GRU scan, TWO independent 16-row machines, no cache fences.
//    512 blocks x 256 threads, 2 blocks/CU. machine = blockIdx>>8 (rows
//    m*16..m*16+15); cb = blockIdx&255 owns cols cb*4..cb*4+3. Weights
//    LDS-resident; h / r*h exchanged via coherent sc0sc1 accesses at LLC.
//    Blocks cb<4 additionally write out[.][t-1] as full-line coalesced
//    stores from the h registers they load anyway for phase A.
// ---------------------------------------------------------------------------
__global__ __launch_bounds__(256, 2) void k_scan(
    const int* __restrict__ tok, const float* __restrict__ xpre,
    const float* __restrict__ whT, float* h, float* rh,
    float* __restrict__ out_nr, float* __restrict__ out_ni,
    float* __restrict__ out_fcr, float* __restrict__ out_fci, unsigned* bar) {
  __shared__ float wa[8][1024];   // cols 0..3 = Whr[j0..], 4..7 = Whu[j0..]
  __shared__ float wcl[4][1024];  // Whc[j0..]

  const int tid = threadIdx.x;
  const int machine = blockIdx.x >> 8;   // 0/1; blocks c and c+256 share a CU
  const int cb = blockIdx.x & 255;       // column block
  const int j0 = cb * 4;
  const int grp = cb >> 4;
  unsigned* mybar = bar + (machine << 10);

  for (int idx = tid; idx < 8192; idx += 256) {
    int c = idx >> 10, k = idx & 1023;
    size_t gofs = (c < 4) ? 0u : 1048576u;
    wa[c][k] = whT[gofs + (size_t)(j0 + (c & 3)) * 1024 + k];
  }
  for (int idx = tid; idx < 4096; idx += 256) {
    int c = idx >> 10, k = idx & 1023;
    wcl[c][k] = whT[2097152u + (size_t)(j0 + c) * 1024 + k];
  }
  __syncthreads();

  // seed anti-phase so the co-resident machine's compute overlaps our waits
  if (machine == 1) {
    __builtin_amdgcn_s_sleep(16);
    __builtin_amdgcn_s_sleep(16);
  }

  const int wv = tid >> 6;
  const int lane = tid & 63;
  const int r0 = machine * 16 + wv * 4;  // wave's 4 global batch rows
  const int kl = lane << 2;              // lane k-slice base (floats)
  // phase-A result mapping: idx = lane&31 -> (row idx>>3, gate-col idx&7)
  const int ia = (lane & 31) >> 3;
  const int arow = r0 + ia;
  const int ac = lane & 7;               // 0..3 = r cols, 4..7 = u cols
  const int acol = j0 + (ac & 3);
  // phase-B result mapping: idx = lane&15 -> (row idx>>2, c-col idx&3)
  const int ib = (lane & 15) >> 2;
  const int brow = r0 + ib;
  const int bcol = j0 + (lane & 3);
  const int usrc = (ib << 3) + 4 + (lane & 3);  // lane holding u for (ib,col)

  // writer-block (cb<4) output mapping: global k = cb*256 + lane*4
  float* warr = (cb < 2) ? out_nr : out_ni;
  const int wk = ((cb & 1) << 8) + (lane << 2);
  float* fcarr = (cb < 2) ? out_fcr : out_fci;

  float u_s = 0.f;
  unsigned round = 0;

  for (int t = 0; t < SS; ++t) {
    // per-lane scalar prefetch (latency hides under phase-A GEMM)
    const int tva = tok[(size_t)arow * SS + t];
    const float xru_s = (ac < 4)
        ? xpre[(size_t)tva * 1024 + acol]
        : xpre[262144u + (size_t)tva * 1024 + acol];
    const float ho_s = ld_c1(h + (size_t)arow * 1024 + acol);   // for r*h
    const int tvb = tok[(size_t)brow * SS + t];
    const float xc_s = xpre[524288u + (size_t)tvb * 1024 + bcol];
    const float hob_s = ld_c1(h + (size_t)brow * 1024 + bcol);  // state upd

    // ---------------- Phase A: vals[i*8+c] = sum_k h[r0+i][k]*wa[c][k]
    float vals[32];
#pragma unroll
    for (int q = 0; q < 32; ++q) vals[q] = 0.f;

    {
      float2 hva[8], hvb[8];
      auto loadg = [&](float2(&buf)[8], int g) {
        const int kb = (g << 8) + kl;
#pragma unroll
        for (int i = 0; i < 4; ++i) {
          const float* p = h + (size_t)(r0 + i) * 1024 + kb;
          buf[i * 2] = ld_c2(p);
          buf[i * 2 + 1] = ld_c2(p + 2);
        }
      };
      auto outwrite = [&](float2(&buf)[8]) {  // writer blocks: out[.][t-1]
#pragma unroll
        for (int i = 0; i < 4; ++i) {
          float4 o;
          o.x = buf[i * 2].x;     o.y = buf[i * 2].y;
          o.z = buf[i * 2 + 1].x; o.w = buf[i * 2 + 1].y;
          *(float4*)(warr + ((size_t)(r0 + i) * SS + (t - 1)) * 512 + wk) = o;
        }
      };
      auto fmasA = [&](float2(&cur)[8], int g) {
        const int k0 = (g << 8) + kl;
#pragma unroll
        for (int c = 0; c < 8; ++c) {
          const float4 wv4 = *(const float4*)(&wa[c][k0]);
#pragma unroll
          for (int i = 0; i < 4; ++i) {
            vals[i * 8 + c] = fmaf(cur[i * 2].x, wv4.x, vals[i * 8 + c]);
            vals[i * 8 + c] = fmaf(cur[i * 2].y, wv4.y, vals[i * 8 + c]);
            vals[i * 8 + c] = fmaf(cur[i * 2 + 1].x, wv4.z, vals[i * 8 + c]);
            vals[i * 8 + c] = fmaf(cur[i * 2 + 1].y, wv4.w, vals[i * 8 + c]);
          }
        }
      };
      loadg(hva, 0);
      loadg(hvb, 1); if (cb == 0 && t > 0) outwrite(hva); fmasA(hva, 0);
      loadg(hva, 2); if (cb == 1 && t > 0) outwrite(hvb); fmasA(hvb, 1);
      loadg(hvb, 3); if (cb == 2 && t > 0) outwrite(hva); fmasA(hva, 2);
                     if (cb == 3 && t > 0) outwrite(hvb); fmasA(hvb, 3);
    }

    {
      // pair_reduce sequence: value idx migrates to lane idx
#pragma unroll
      for (int o = 1, n = 32; n > 1; o <<= 1, n >>= 1) {
#pragma unroll
        for (int k = 0; k < 16; ++k) {
          if (k < (n >> 1)) {
            float a = vals[2 * k], b = vals[2 * k + 1];
            float sent = (lane & o) ? a : b;
            float recv = __shfl_xor(sent, o);
            vals[k] = ((lane & o) ? b : a) + recv;
          }
        }
      }
    }
    const float pre_a = vals[0] + __shfl_xor(vals[0], 32);

    const float gate = sigmoid_f(pre_a + xru_s);
    if (ac < 4) {
      if (lane < 32) st_c1(rh + (size_t)arow * 1024 + acol, gate * ho_s);
    } else {
      u_s = gate;
    }
    grid_barrier(mybar, grp, ++round);

    // ---------------- Phase B: v2[i*4+c] = sum_k rh[r0+i][k]*wcl[c][k]
    float v2[16];
#pragma unroll
    for (int q = 0; q < 16; ++q) v2[q] = 0.f;

    {
      float2 rva[8], rvb[8];
      auto loadg2 = [&](float2(&buf)[8], int g) {
        const int kb = (g << 8) + kl;
#pragma unroll
        for (int i = 0; i < 4; ++i) {
          const float* p = rh + (size_t)(r0 + i) * 1024 + kb;
          buf[i * 2] = ld_c2(p);
          buf[i * 2 + 1] = ld_c2(p + 2);
        }
      };
      auto fmasB = [&](float2(&cur)[8], int g) {
        const int k0 = (g << 8) + kl;
#pragma unroll
        for (int c = 0; c < 4; ++c) {
          const float4 wv4 = *(const float4*)(&wcl[c][k0]);
#pragma unroll
          for (int i = 0; i < 4; ++i) {
            v2[i * 4 + c] = fmaf(cur[i * 2].x, wv4.x, v2[i * 4 + c]);
            v2[i * 4 + c] = fmaf(cur[i * 2].y, wv4.y, v2[i * 4 + c]);
            v2[i * 4 + c] = fmaf(cur[i * 2 + 1].x, wv4.z, v2[i * 4 + c]);
            v2[i * 4 + c] = fmaf(cur[i * 2 + 1].y, wv4.w, v2[i * 4 + c]);
          }
        }
      };
      loadg2(rva, 0);
      loadg2(rvb, 1); fmasB(rva, 0);
      loadg2(rva, 2); fmasB(rvb, 1);
      loadg2(rvb, 3); fmasB(rva, 2);
                      fmasB(rvb, 3);
    }

    {
#pragma unroll
      for (int o = 1, n = 16; n > 1; o <<= 1, n >>= 1) {
#pragma unroll
        for (int k = 0; k < 8; ++k) {
          if (k < (n >> 1)) {
            float a = v2[2 * k], b = v2[2 * k + 1];
            float sent = (lane & o) ? a : b;
            float recv = __shfl_xor(sent, o);
            v2[k] = ((lane & o) ? b : a) + recv;
          }
        }
      }
    }
    float cpre = v2[0] + __shfl_xor(v2[0], 16);
    cpre += __shfl_xor(cpre, 32);

    const float cc = tanh_f(cpre + xc_s);
    const float uu = __shfl(u_s, usrc);
    const float hn = (1.f - uu) * hob_s + uu * cc;
    if (lane < 16) st_c1(h + (size_t)brow * 1024 + bcol, hn);
    grid_barrier(mybar, grp, ++round);
  }

  // epilogue: writer blocks emit out[.][SS-1] and the final carry
  if (cb < 4) {
#pragma unroll
    for (int i = 0; i < 4; ++i) {
      const int row = r0 + i;
      const float* p = h + (size_t)row * 1024 + (cb << 8) + kl;
      float2 a = ld_c2(p);
      float2 b2 = ld_c2(p + 2);
      float4 o; o.x = a.x; o.y = a.y; o.z = b2.x; o.w = b2.y;
      *(float4*)(warr + ((size_t)row * SS + (SS - 1)) * 512 + wk) = o;
      *(float4*)(fcarr + (size_t)row * 512 + wk) = o;
    }
  }
}

// ---------------------------------------------------------------------------
// 4) Fused tail: LayerNorm (in LDS, writes normalized n_r/n_i back) + logits.
// ---------------------------------------------------------------------------
__global__ __launch_bounds__(256) void k_tail(
    float* __restrict__ nr, float* __restrict__ ni,  // raw in, normalized out
    const float* __restrict__ sr, const float* __restrict__ br_,
    const float* __restrict__ si, const float* __restrict__ bi_,
    const float* __restrict__ Wrc, const float* __restrict__ Wic,
    const float* __restrict__ brc, const float* __restrict__ bic,
    float* __restrict__ out) {
  __shared__ float tr[16][512];
  __shared__ float ti[16][512];
  const long long r0 = (long long)blockIdx.x * 16;
  const int tid = threadIdx.x;
  for (int idx = tid; idx < 16 * 512; idx += 256) {
    int rr = idx >> 9, k = idx & 511;
    tr[rr][k] = nr[(r0 + rr) * 512 + k];
    ti[rr][k] = ni[(r0 + rr) * 512 + k];
  }
  __syncthreads();

  // LayerNorm: 32 (array,row) pairs over 4 waves
  {
    const int wv = tid >> 6, ln = tid & 63;
#pragma unroll
    for (int pp = 0; pp < 8; ++pp) {
      const int p = wv * 8 + pp;
      const int arr = p >> 4;   // 0 = real, 1 = imag
      const int row = p & 15;
      float* t = arr ? &ti[row][0] : &tr[row][0];
      float v[8];
      float s = 0.f, q = 0.f;
#pragma unroll
      for (int j = 0; j < 8; ++j) {
        v[j] = t[ln + j * 64];
        s += v[j];
        q += v[j] * v[j];
      }
#pragma unroll
      for (int o = 32; o >= 1; o >>= 1) {
        s += __shfl_xor(s, o);
        q += __shfl_xor(q, o);
      }
      const float mean = s * (1.f / 512.f);
      const float rstd = rsqrtf(q * (1.f / 512.f) - mean * mean + 1e-6f);
      const float* sc = arr ? si : sr;
      const float* bs = arr ? bi_ : br_;
      float* gout = (arr ? ni : nr) + (r0 + row) * 512;
#pragma unroll
      for (int j = 0; j < 8; ++j) {
        const int k = ln + j * 64;
        float n = (v[j] - mean) * rstd * sc[k] + bs[k];
        t[k] = n;
        gout[k] = n;
      }
    }
  }
  __syncthreads();

  // logits GEMM: thread = one vocab column, 16 rows each.
  const int c = tid;
  float aR[16], aI[16];
#pragma unroll
  for (int i = 0; i < 16; ++i) { aR[i] = 0.f; aI[i] = 0.f; }
  for (int k0 = 0; k0 < 512; k0 += 4) {
    float wr[4], wi[4];
#pragma unroll
    for (int i = 0; i < 4; ++i) {
      wr[i] = Wrc[(size_t)(k0 + i) * 256 + c];
      wi[i] = Wic[(size_t)(k0 + i) * 256 + c];
    }
#pragma unroll
    for (int rrr = 0; rrr < 16; ++rrr) {
      const float4 vr = *(const float4*)(&tr[rrr][k0]);
      const float4 vi = *(const float4*)(&ti[rrr][k0]);
      aR[rrr] = fmaf(vr.x, wr[0], aR[rrr]);
      aR[rrr] = fmaf(vr.y, wr[1], aR[rrr]);
      aR[rrr] = fmaf(vr.z, wr[2], aR[rrr]);
      aR[rrr] = fmaf(vr.w, wr[3], aR[rrr]);
      aI[rrr] = fmaf(vi.x, wi[0], aI[rrr]);
      aI[rrr] = fmaf(vi.y, wi[1], aI[rrr]);
      aI[rrr] = fmaf(vi.z, wi[2], aI[rrr]);
      aI[rrr] = fmaf(vi.w, wi[3], aI[rrr]);
    }
  }
  const float bR = brc[c], bI = bic[c];
#pragma unroll
  for (int rrr = 0; rrr < 16; ++rrr) {
    float x = aR[rrr] + bR, y = aI[rrr] + bI;
    out[(r0 + rrr) * 256 + c] = x * x + y * y;
  }
}

// ---------------------------------------------------------------------------
// launch
// ---------------------------------------------------------------------------
extern "C" void kernel_launch(void* const* d_in, const int* in_sizes, int n_in,
                              void* d_out, int out_size, void* d_ws, size_t ws_size,
                              hipStream_t stream) {
  const int* tok = (const int*)d_in[0];
  const float* Er = (const float*)d_in[1];
  const float* Ei = (const float*)d_in[2];
  const float* Wr = (const float*)d_in[3];
  const float* br = (const float*)d_in[4];
  const float* Wu = (const float*)d_in[5];
  const float* bu = (const float*)d_in[6];
  const float* Wc = (const float*)d_in[7];
  const float* bc = (const float*)d_in[8];
  const float* lrs = (const float*)d_in[9];
  const float* lrb = (const float*)d_in[10];
  const float* lis = (const float*)d_in[11];
  const float* lib = (const float*)d_in[12];
  const float* Wrc = (const float*)d_in[13];
  const float* brc = (const float*)d_in[14];
  const float* Wic = (const float*)d_in[15];
  const float* bic = (const float*)d_in[16];

  float* out = (float*)d_out;
  float* fcr = out;                       // [32][512]
  float* fci = out + 16384;               // [32][512]
  float* nr = out + 32768;                // [32][2048][512]
  float* ni = nr + 33554432;              // [32][2048][512]
  float* lg = ni + 33554432;              // [32][2048][256]

  float* ws = (float*)d_ws;
  unsigned* bar = (unsigned*)ws;          // 2 machines x 4KB barrier state
  float* h = ws + 2048;                   // [32][1024]
  float* rh = ws + 34816;                 // [32][1024]
  float* xpre = ws + 67584;               // [3][256][1024]
  float* whT = ws + 854016;               // [3][1024][1024]

  hipMemsetAsync(bar, 0, 8192, stream);
  hipMemsetAsync(h, 0, 32 * 1024 * sizeof(float), stream);

  k_transpose<<<3072, 256, 0, stream>>>(Wr, Wu, Wc, whT);
  k_xpre<<<192, 256, 0, stream>>>(Er, Ei, Wr, Wu, Wc, br, bu, bc, xpre);
  k_scan<<<512, 256, 0, stream>>>(tok, xpre, whT, h, rh, nr, ni, fcr, fci, bar);
  k_tail<<<4096, 256, 0, stream>>>(nr, ni, lrs, lrb, lis, lib, Wrc, Wic, brc, bic, lg);
}